// Round 16
// baseline (71.053 us; speedup 1.0000x reference)
//
#include <hip/hip_runtime.h>
#include <stdint.h>

#define T_STEPS 2048
#define NCHUNK  86            // 85 full 24-step chunks + one 8-step tail
#define LARGEF  1.0e9f
#define NB      512
typedef unsigned long long u64;
typedef unsigned uint2v __attribute__((ext_vector_type(2)));

__device__ __forceinline__ int par6(int x) { return __builtin_popcount((unsigned)x) & 1; }

// dual-basis functionals C; exchange masks m={1,2,7,15,16,32} (verified r2-r15)
constexpr int CARR[6] = {5, 6, 12, 8, 16, 32};

template<int CTRL>
__device__ __forceinline__ float xdpp(float x) {
  return __int_as_float(__builtin_amdgcn_update_dpp(0, __float_as_int(x), CTRL, 0xF, 0xF, true));
}
template<int CTRL>
__device__ __forceinline__ unsigned xdpp_u(unsigned x) {
  return (unsigned)__builtin_amdgcn_update_dpp(0, (int)x, CTRL, 0xF, 0xF, true);
}
__device__ __forceinline__ unsigned selmask_u(unsigned a_false, unsigned b_true, u64 m) {
  unsigned out;
  asm("v_cndmask_b32 %0, %1, %2, %3" : "=v"(out) : "v"(a_false), "v"(b_true), "s"(m));
  return out;
}
__device__ __forceinline__ unsigned exch16_u(unsigned x, u64 mrx) {
#if __has_builtin(__builtin_amdgcn_permlane16_swap)
  uint2v r = __builtin_amdgcn_permlane16_swap(x, x, false, false);
  return selmask_u(r.y, r.x, mrx);
#else
  (void)mrx;
  return (unsigned)__builtin_amdgcn_ds_swizzle((int)x, 0x401F);
#endif
}
__device__ __forceinline__ unsigned exch32_u(unsigned x, u64 mrx) {
#if __has_builtin(__builtin_amdgcn_permlane32_swap)
  uint2v r = __builtin_amdgcn_permlane32_swap(x, x, false, false);
  return selmask_u(r.y, r.x, mrx);
#else
  (void)mrx;
  return (unsigned)__shfl_xor((int)x, 32, 64);
#endif
}
template<int PH>
__device__ __forceinline__ float exchf(float x, const u64 (&mrx)[2]) {
  if constexpr (PH == 0) return xdpp<0xB1>(x);        // xor 1
  else if constexpr (PH == 1) return xdpp<0x4E>(x);   // xor 2
  else if constexpr (PH == 2) return xdpp<0x141>(x);  // xor 7
  else if constexpr (PH == 3) return xdpp<0x140>(x);  // xor 15
  else if constexpr (PH == 4) return __uint_as_float(exch16_u(__float_as_uint(x), mrx[0]));
  else return __uint_as_float(exch32_u(__float_as_uint(x), mrx[1]));
}
template<int PH>
__device__ __forceinline__ unsigned exchu(unsigned x, const u64 (&mrx)[2]) {
  if constexpr (PH == 0) return xdpp_u<0xB1>(x);
  else if constexpr (PH == 1) return xdpp_u<0x4E>(x);
  else if constexpr (PH == 2) return xdpp_u<0x141>(x);
  else if constexpr (PH == 3) return xdpp_u<0x140>(x);
  else if constexpr (PH == 4) return exch16_u(x, mrx[0]);
  else return exch32_u(x, mrx[1]);
}

struct Phc {
  float sae[6], sbe[6];
  unsigned clsm[6];  // v_cmp_class mask: pd ? (-inf|-norm|-den)=0x1C : (+den|+norm|+inf)=0x380
  unsigned pdu[6];   // decoded-bit constant per phase
  u64 pdm[6];        // uniform mask: lanes with odd own-pred parity
  u64 mrx[2];        // permlane swap r.x-select masks
};

__device__ __forceinline__ void mk_sasb(int lane, int ph, float& sae, float& sbe, int& pdv) {
  pdv = par6(lane & CARR[ph]);
  int t = 0;
#pragma unroll
  for (int j = 0; j < 5; ++j) t |= par6(lane & CARR[(ph + 1 + j) % 6]) << j;
  t |= pdv << 5;
  const float sa = 1.0f - 2.0f * (float)par6(t & 45);   // poly 1011011
  const float sb = 1.0f - 2.0f * (float)par6(t & 60);   // poly 1111001
  sae = pdv ? -sa : sa;
  sbe = pdv ? -sb : sb;
}

__device__ __forceinline__ void mk_mrx(int lane, u64 (&mrx)[2]) {
  const u64 ODD16 = 0xFFFF0000FFFF0000ull, HI32 = 0xFFFFFFFF00000000ull;
#if __has_builtin(__builtin_amdgcn_permlane16_swap)
  {
    uint2v r = __builtin_amdgcn_permlane16_swap((unsigned)lane, (unsigned)lane, false, false);
    mrx[0] = (((unsigned)__builtin_amdgcn_readlane((int)r.x, 0) == 16u)) ? ~ODD16 : ODD16;
  }
#else
  mrx[0] = 0;
#endif
#if __has_builtin(__builtin_amdgcn_permlane32_swap)
  {
    uint2v r = __builtin_amdgcn_permlane32_swap((unsigned)lane, (unsigned)lane, false, false);
    mrx[1] = (((unsigned)__builtin_amdgcn_readlane((int)r.x, 0) == 32u)) ? ~HI32 : HI32;
  }
#else
  mrx[1] = 0;
#endif
}

__device__ __forceinline__ void mkconsts(int lane, Phc& p) {
#pragma unroll
  for (int ph = 0; ph < 6; ++ph) {
    int pdv;
    mk_sasb(lane, ph, p.sae[ph], p.sbe[ph], pdv);
    p.clsm[ph] = pdv ? 0x01Cu : 0x380u;
    p.pdu[ph] = (unsigned)pdv;
    p.pdm[ph] = __ballot(pdv != 0);
  }
  mk_mrx(lane, p.mrx);
}

// ---- hoisted branch metrics for a chunk (independent ILP block) ----
template<int N>
__device__ __forceinline__ void bmcalc(const float4 (&fy)[12], float (&bm)[24],
                                       const float (&sae)[6], const float (&sbe)[6]) {
#pragma unroll
  for (int k = 0; k < N; ++k) {
    const int ph = k % 6;
    const float y0 = (k & 1) ? fy[k >> 1].z : fy[k >> 1].x;
    const float y1 = (k & 1) ? fy[k >> 1].w : fy[k >> 1].y;
    bm[k] = fmaf(sae[ph], y0, sbe[ph] * y1);   // bit-exact vs ref
  }
}

// ---- forward core: N ACS steps; dw = 2*dw + d (d_K lands at bit N-1-K) ----
// d via v_cmp_class(D, clsm): per-lane direction, tie(+-0) -> 0. == verified sign-xor rule.
template<int N, int K>
__device__ __forceinline__ void acs(float& cum, unsigned& dw, const float (&bm)[24],
                                    const unsigned (&clsm)[6], const u64 (&mrx)[2]) {
  if constexpr (K < N) {
    constexpr int ph = K % 6;
    const float ex = exchf<ph>(cum, mrx);
    const float cA = cum + bm[K];   // own-pred candidate
    const float cB = ex - bm[K];    // partner-pred candidate
    const float D = cA - cB;        // sign exact; zero iff true tie
    cum = fminf(cA, cB);
    asm("v_cmp_class_f32 vcc, %1, %2\n\t"
        "v_addc_co_u32 %0, vcc, %0, %0, vcc"
        : "+v"(dw) : "v"(D), "v"(clsm[ph]) : "vcc");
    acs<N, K + 1>(cum, dw, bm, clsm, mrx);
  }
}

// ---- chunk word reconstruction from d-bits (tp = d XOR pd; verified r10-r15) ----
template<int N, int K>
__device__ __forceinline__ void wrec(unsigned& word, unsigned& dws, const unsigned (&pdu)[6],
                                     const u64 (&pdm)[6], const u64 (&mrx)[2]) {
  if constexpr (K < N) {
    constexpr int ph = K % 6;
    const unsigned exw = exchu<ph>(word, mrx);
    asm("v_cmp_gt_i32 vcc, 0, %1\n\t"
        "v_add_u32 %1, %1, %1\n\t"
        "s_xor_b64 vcc, vcc, %3\n\t"
        "v_cndmask_b32 %0, %0, %2, vcc"
        : "+v"(word), "+v"(dws)
        : "v"(exw), "s"(pdm[ph]) : "vcc");
    word |= pdu[ph] << (6 + K);
    wrec<N, K + 1>(word, dws, pdu, pdm, mrx);
  }
}

// ---- terminal argmin over true states (tie -> smallest state) ----
__device__ __forceinline__ int term_argmin(float cum, int lane) {
  // final labeling = phase 2048%6 = 2: state bit j from C[(2+j)%6] = {12,8,16,32,5,6}
  const int stf = par6(lane & 12) | (par6(lane & 8) << 1) | (par6(lane & 16) << 2) |
                  (par6(lane & 32) << 3) | (par6(lane & 5) << 4) | (par6(lane & 6) << 5);
  float v = cum; int bs = stf; int bl = lane;
#pragma unroll
  for (int off = 32; off >= 1; off >>= 1) {
    const float ov = __shfl_xor(v, off, 64);
    const int os = __shfl_xor(bs, off, 64);
    const int ol = __shfl_xor(bl, off, 64);
    if (ov < v || (ov == v && os < bs)) { v = ov; bs = os; bl = ol; }
  }
  return bl;
}

// ========== fused kernel: wave0 forward -> 8-wave wrec (in-place) -> wave0 traceback ==========
// waves_per_eu(4,4): VGPR budget 128/wave (keeps bm+chunk buffers in regs; r15's 48-VGPR
// allocation sank the prefetch and cost ~6 us). 8 waves x 128 VGPR still fits 2 blocks/CU.
__global__ __attribute__((amdgpu_waves_per_eu(4, 4))) __launch_bounds__(512)
void vit_all(const float* __restrict__ in, float* __restrict__ out) {
  __shared__ float y_lds[2 * T_STEPS];     // 16 KB staged input row
  __shared__ unsigned buf[NCHUNK][64];     // 21.5 KB: d-words, then path/anc words (in-place)
  __shared__ int lam_sh;

  const int tid = threadIdx.x;
  const int lane = tid & 63;
  const int wv = tid >> 6;
  const int b = blockIdx.x;

  // ---- stage y (8 waves, coalesced float4) ----
  {
    const float4* g = (const float4*)(in + (size_t)b * (2 * T_STEPS));
    float4* l = (float4*)y_lds;
    l[tid] = g[tid];
    l[tid + 512] = g[tid + 512];
  }
  Phc p;
  mkconsts(lane, p);
  __syncthreads();

  // ---- forward ACS (wave0 only; other waves wait at barrier, consuming no issue slots) ----
  if (wv == 0) {
    float cum = (lane == 0) ? 0.0f : LARGEF;
    float bm[24];
    float4 cur[12], nxt[12];
    const float4* y4 = (const float4*)y_lds;
    unsigned dw = 0;   // left-shifting accumulator; stale high bits discarded by wrec shifts
#pragma unroll
    for (int j = 0; j < 12; ++j) cur[j] = y4[j];               // chunk 0
    for (int cc = 0; cc < 42; ++cc) {
      const int c0 = 2 * cc;
      bmcalc<24>(cur, bm, p.sae, p.sbe);
#pragma unroll
      for (int j = 0; j < 12; ++j) nxt[j] = y4[12 * (c0 + 1) + j];   // prefetch c0+1
      acs<24, 0>(cum, dw, bm, p.clsm, p.mrx);
      buf[c0][lane] = dw;
      bmcalc<24>(nxt, bm, p.sae, p.sbe);
#pragma unroll
      for (int j = 0; j < 12; ++j) cur[j] = y4[12 * (c0 + 2) + j];   // prefetch c0+2
      acs<24, 0>(cum, dw, bm, p.clsm, p.mrx);
      buf[c0 + 1][lane] = dw;
    }
    // chunk 84 from cur; tail (steps 2040..2047) = float4 idx 1020..1023
    bmcalc<24>(cur, bm, p.sae, p.sbe);
#pragma unroll
    for (int j = 0; j < 4; ++j) nxt[j] = y4[1020 + j];
    acs<24, 0>(cum, dw, bm, p.clsm, p.mrx);
    buf[84][lane] = dw;
    bmcalc<8>(nxt, bm, p.sae, p.sbe);
    acs<8, 0>(cum, dw, bm, p.clsm, p.mrx);
    buf[85][lane] = dw;

    const int bl = term_argmin(cum, lane);
    if (lane == 0) lam_sh = bl;
  }
  __syncthreads();

  // ---- word reconstruction: 8 waves, ~11 chunks each, in-place on buf ----
  {
    const int cbeg = wv * 11;
    const int cend = (cbeg + 11 < NCHUNK) ? cbeg + 11 : NCHUNK;
    for (int c = cbeg; c < cend; ++c) {
      const unsigned dw = buf[c][lane];     // each slot read once, written once, same thread
      unsigned word = (unsigned)lane;
      if (c == NCHUNK - 1) {
        unsigned dws = dw << 24;
        wrec<8, 0>(word, dws, p.pdu, p.pdm, p.mrx);
      } else {
        unsigned dws = dw << 8;
        wrec<24, 0>(word, dws, p.pdu, p.pdm, p.mrx);
      }
      buf[c][lane] = word;
    }
  }
  __syncthreads();

  // ---- traceback: wave0, 86 chunk hops with prefetch ----
  if (wv == 0) {
    int lam = __builtin_amdgcn_readfirstlane(lam_sh);
    const size_t ob = (size_t)b * T_STEPS;
    unsigned row = buf[NCHUNK - 1][lane];
    for (int c = NCHUNK - 1; c >= 0; --c) {
      unsigned nrow = 0;
      if (c > 0) nrow = buf[c - 1][lane];          // prefetch (addr indep of lam)
      const unsigned w = (unsigned)__builtin_amdgcn_readlane((int)row, lam);
      const int nb = (c == NCHUNK - 1) ? 8 : 24;
      if (lane < nb) out[ob + c * 24 + lane] = (float)((w >> (6 + lane)) & 1u);
      lam = (int)(w & 63u);
      row = nrow;
    }
  }
}

extern "C" void kernel_launch(void* const* d_in, const int* in_sizes, int n_in,
                              void* d_out, int out_size, void* d_ws, size_t ws_size,
                              hipStream_t stream) {
  const float* in = (const float*)d_in[0];
  float* out = (float*)d_out;
  (void)in_sizes; (void)n_in; (void)out_size; (void)d_ws; (void)ws_size;
  vit_all<<<dim3(NB), dim3(512), 0, stream>>>(in, out);
}

// Round 17
// 68.483 us; speedup vs baseline: 1.0375x; 1.0375x over previous
//
#include <hip/hip_runtime.h>
#include <stdint.h>

#define T_STEPS 2048
#define NCHUNK  86            // 85 full 24-step chunks + one 8-step tail
#define LARGEF  1.0e9f
#define NB      512
typedef unsigned long long u64;
typedef unsigned uint2v __attribute__((ext_vector_type(2)));

__device__ __forceinline__ int par6(int x) { return __builtin_popcount((unsigned)x) & 1; }

// dual-basis functionals C; exchange masks m={1,2,7,15,16,32} (verified r2-r16)
constexpr int CARR[6] = {5, 6, 12, 8, 16, 32};

template<int CTRL>
__device__ __forceinline__ float xdpp(float x) {
  return __int_as_float(__builtin_amdgcn_update_dpp(0, __float_as_int(x), CTRL, 0xF, 0xF, true));
}
template<int CTRL>
__device__ __forceinline__ unsigned xdpp_u(unsigned x) {
  return (unsigned)__builtin_amdgcn_update_dpp(0, (int)x, CTRL, 0xF, 0xF, true);
}
__device__ __forceinline__ unsigned selmask_u(unsigned a_false, unsigned b_true, u64 m) {
  unsigned out;
  asm("v_cndmask_b32 %0, %1, %2, %3" : "=v"(out) : "v"(a_false), "v"(b_true), "s"(m));
  return out;
}
__device__ __forceinline__ unsigned exch16_u(unsigned x, u64 mrx) {
#if __has_builtin(__builtin_amdgcn_permlane16_swap)
  uint2v r = __builtin_amdgcn_permlane16_swap(x, x, false, false);
  return selmask_u(r.y, r.x, mrx);
#else
  (void)mrx;
  return (unsigned)__builtin_amdgcn_ds_swizzle((int)x, 0x401F);
#endif
}
__device__ __forceinline__ unsigned exch32_u(unsigned x, u64 mrx) {
#if __has_builtin(__builtin_amdgcn_permlane32_swap)
  uint2v r = __builtin_amdgcn_permlane32_swap(x, x, false, false);
  return selmask_u(r.y, r.x, mrx);
#else
  (void)mrx;
  return (unsigned)__shfl_xor((int)x, 32, 64);
#endif
}
template<int PH>
__device__ __forceinline__ float exchf(float x, const u64 (&mrx)[2]) {
  if constexpr (PH == 0) return xdpp<0xB1>(x);        // xor 1
  else if constexpr (PH == 1) return xdpp<0x4E>(x);   // xor 2
  else if constexpr (PH == 2) return xdpp<0x141>(x);  // xor 7
  else if constexpr (PH == 3) return xdpp<0x140>(x);  // xor 15
  else if constexpr (PH == 4) return __uint_as_float(exch16_u(__float_as_uint(x), mrx[0]));
  else return __uint_as_float(exch32_u(__float_as_uint(x), mrx[1]));
}
template<int PH>
__device__ __forceinline__ unsigned exchu(unsigned x, const u64 (&mrx)[2]) {
  if constexpr (PH == 0) return xdpp_u<0xB1>(x);
  else if constexpr (PH == 1) return xdpp_u<0x4E>(x);
  else if constexpr (PH == 2) return xdpp_u<0x141>(x);
  else if constexpr (PH == 3) return xdpp_u<0x140>(x);
  else if constexpr (PH == 4) return exch16_u(x, mrx[0]);
  else return exch32_u(x, mrx[1]);
}

// ---- register pins: force values to live in VGPRs at this point (defeat load sinking) ----
__device__ __forceinline__ void pin4(float4& v) {
  asm volatile("" : "+v"(v.x), "+v"(v.y), "+v"(v.z), "+v"(v.w));
}
__device__ __forceinline__ void pinN(float4 (&a)[12]) {
#pragma unroll
  for (int j = 0; j < 12; ++j) pin4(a[j]);
}
__device__ __forceinline__ void pinB(float (&bm)[24]) {
#pragma unroll
  for (int j = 0; j < 24; j += 4)
    asm volatile("" : "+v"(bm[j]), "+v"(bm[j + 1]), "+v"(bm[j + 2]), "+v"(bm[j + 3]));
}

struct Phc {
  float sae[6], sbe[6];
  unsigned clsm[6];  // v_cmp_class mask: pd ? (-inf|-norm|-den)=0x1C : (+den|+norm|+inf)=0x380
  unsigned pdu[6];   // decoded-bit constant per phase
  u64 pdm[6];        // uniform mask: lanes with odd own-pred parity
  u64 mrx[2];        // permlane swap r.x-select masks
};

__device__ __forceinline__ void mk_sasb(int lane, int ph, float& sae, float& sbe, int& pdv) {
  pdv = par6(lane & CARR[ph]);
  int t = 0;
#pragma unroll
  for (int j = 0; j < 5; ++j) t |= par6(lane & CARR[(ph + 1 + j) % 6]) << j;
  t |= pdv << 5;
  const float sa = 1.0f - 2.0f * (float)par6(t & 45);   // poly 1011011
  const float sb = 1.0f - 2.0f * (float)par6(t & 60);   // poly 1111001
  sae = pdv ? -sa : sa;
  sbe = pdv ? -sb : sb;
}

__device__ __forceinline__ void mk_mrx(int lane, u64 (&mrx)[2]) {
  const u64 ODD16 = 0xFFFF0000FFFF0000ull, HI32 = 0xFFFFFFFF00000000ull;
#if __has_builtin(__builtin_amdgcn_permlane16_swap)
  {
    uint2v r = __builtin_amdgcn_permlane16_swap((unsigned)lane, (unsigned)lane, false, false);
    mrx[0] = (((unsigned)__builtin_amdgcn_readlane((int)r.x, 0) == 16u)) ? ~ODD16 : ODD16;
  }
#else
  mrx[0] = 0;
#endif
#if __has_builtin(__builtin_amdgcn_permlane32_swap)
  {
    uint2v r = __builtin_amdgcn_permlane32_swap((unsigned)lane, (unsigned)lane, false, false);
    mrx[1] = (((unsigned)__builtin_amdgcn_readlane((int)r.x, 0) == 32u)) ? ~HI32 : HI32;
  }
#else
  mrx[1] = 0;
#endif
}

__device__ __forceinline__ void mkconsts(int lane, Phc& p) {
#pragma unroll
  for (int ph = 0; ph < 6; ++ph) {
    int pdv;
    mk_sasb(lane, ph, p.sae[ph], p.sbe[ph], pdv);
    p.clsm[ph] = pdv ? 0x01Cu : 0x380u;
    p.pdu[ph] = (unsigned)pdv;
    p.pdm[ph] = __ballot(pdv != 0);
  }
  mk_mrx(lane, p.mrx);
}

// ---- hoisted branch metrics for a chunk (independent ILP block) ----
template<int N>
__device__ __forceinline__ void bmcalc(const float4 (&fy)[12], float (&bm)[24],
                                       const float (&sae)[6], const float (&sbe)[6]) {
#pragma unroll
  for (int k = 0; k < N; ++k) {
    const int ph = k % 6;
    const float y0 = (k & 1) ? fy[k >> 1].z : fy[k >> 1].x;
    const float y1 = (k & 1) ? fy[k >> 1].w : fy[k >> 1].y;
    bm[k] = fmaf(sae[ph], y0, sbe[ph] * y1);   // bit-exact vs ref
  }
}

// ---- forward core: N ACS steps; dw = 2*dw + d (d_K lands at bit N-1-K) ----
// d via v_cmp_class(D, clsm): per-lane direction, tie(+-0) -> 0. == verified sign-xor rule.
template<int N, int K>
__device__ __forceinline__ void acs(float& cum, unsigned& dw, const float (&bm)[24],
                                    const unsigned (&clsm)[6], const u64 (&mrx)[2]) {
  if constexpr (K < N) {
    constexpr int ph = K % 6;
    const float ex = exchf<ph>(cum, mrx);
    const float cA = cum + bm[K];   // own-pred candidate
    const float cB = ex - bm[K];    // partner-pred candidate
    const float D = cA - cB;        // sign exact; zero iff true tie
    cum = fminf(cA, cB);
    asm("v_cmp_class_f32 vcc, %1, %2\n\t"
        "v_addc_co_u32 %0, vcc, %0, %0, vcc"
        : "+v"(dw) : "v"(D), "v"(clsm[ph]) : "vcc");
    acs<N, K + 1>(cum, dw, bm, clsm, mrx);
  }
}

// ---- chunk word reconstruction from d-bits (tp = d XOR pd; verified r10-r16) ----
template<int N, int K>
__device__ __forceinline__ void wrec(unsigned& word, unsigned& dws, const unsigned (&pdu)[6],
                                     const u64 (&pdm)[6], const u64 (&mrx)[2]) {
  if constexpr (K < N) {
    constexpr int ph = K % 6;
    const unsigned exw = exchu<ph>(word, mrx);
    asm("v_cmp_gt_i32 vcc, 0, %1\n\t"
        "v_add_u32 %1, %1, %1\n\t"
        "s_xor_b64 vcc, vcc, %3\n\t"
        "v_cndmask_b32 %0, %0, %2, vcc"
        : "+v"(word), "+v"(dws)
        : "v"(exw), "s"(pdm[ph]) : "vcc");
    word |= pdu[ph] << (6 + K);
    wrec<N, K + 1>(word, dws, pdu, pdm, mrx);
  }
}

// ---- terminal argmin over true states (tie -> smallest state) ----
__device__ __forceinline__ int term_argmin(float cum, int lane) {
  // final labeling = phase 2048%6 = 2: state bit j from C[(2+j)%6] = {12,8,16,32,5,6}
  const int stf = par6(lane & 12) | (par6(lane & 8) << 1) | (par6(lane & 16) << 2) |
                  (par6(lane & 32) << 3) | (par6(lane & 5) << 4) | (par6(lane & 6) << 5);
  float v = cum; int bs = stf; int bl = lane;
#pragma unroll
  for (int off = 32; off >= 1; off >>= 1) {
    const float ov = __shfl_xor(v, off, 64);
    const int os = __shfl_xor(bs, off, 64);
    const int ol = __shfl_xor(bl, off, 64);
    if (ov < v || (ov == v && os < bs)) { v = ov; bs = os; bl = ol; }
  }
  return bl;
}

// ========== fused kernel: wave0 forward -> 8-wave wrec (in-place) -> wave0 traceback ==========
__global__ __launch_bounds__(512) void vit_all(const float* __restrict__ in,
                                               float* __restrict__ out) {
  __shared__ float y_lds[2 * T_STEPS];     // 16 KB staged input row
  __shared__ unsigned buf[NCHUNK][64];     // 21.5 KB: d-words, then path/anc words (in-place)
  __shared__ int lam_sh;

  const int tid = threadIdx.x;
  const int lane = tid & 63;
  const int wv = tid >> 6;
  const int b = blockIdx.x;

  // ---- stage y (8 waves, coalesced float4) ----
  {
    const float4* g = (const float4*)(in + (size_t)b * (2 * T_STEPS));
    float4* l = (float4*)y_lds;
    l[tid] = g[tid];
    l[tid + 512] = g[tid + 512];
  }
  Phc p;
  mkconsts(lane, p);
  __syncthreads();

  // ---- forward ACS (wave0 only; other waves wait at barrier, consuming no issue slots) ----
  if (wv == 0) {
    float cum = (lane == 0) ? 0.0f : LARGEF;
    float bm[24];
    float4 cur[12], nxt[12];
    const float4* y4 = (const float4*)y_lds;
    unsigned dw;
#pragma unroll
    for (int j = 0; j < 12; ++j) cur[j] = y4[j];               // chunk 0
    pinN(cur);
    for (int cc = 0; cc < 42; ++cc) {
      const int c0 = 2 * cc;
      bmcalc<24>(cur, bm, p.sae, p.sbe);
      pinB(bm);
#pragma unroll
      for (int j = 0; j < 12; ++j) nxt[j] = y4[12 * (c0 + 1) + j];   // prefetch c0+1
      dw = 0; acs<24, 0>(cum, dw, bm, p.clsm, p.mrx);
      buf[c0][lane] = dw;
      pinN(nxt);                      // loads completed under acs; materialize now
      bmcalc<24>(nxt, bm, p.sae, p.sbe);
      pinB(bm);
#pragma unroll
      for (int j = 0; j < 12; ++j) cur[j] = y4[12 * (c0 + 2) + j];   // prefetch c0+2
      dw = 0; acs<24, 0>(cum, dw, bm, p.clsm, p.mrx);
      buf[c0 + 1][lane] = dw;
      pinN(cur);
    }
    // cur = chunk 84; tail (steps 2040..2047) = float4 idx 1020..1023
    bmcalc<24>(cur, bm, p.sae, p.sbe);
    pinB(bm);
#pragma unroll
    for (int j = 0; j < 4; ++j) nxt[j] = y4[1020 + j];
    dw = 0; acs<24, 0>(cum, dw, bm, p.clsm, p.mrx);
    buf[84][lane] = dw;
    bmcalc<8>(nxt, bm, p.sae, p.sbe);
    dw = 0; acs<8, 0>(cum, dw, bm, p.clsm, p.mrx);
    buf[85][lane] = dw;

    const int bl = term_argmin(cum, lane);
    if (lane == 0) lam_sh = bl;
  }
  __syncthreads();

  // ---- word reconstruction: 8 waves, ~11 chunks each, in-place on buf ----
  {
    const int cbeg = wv * 11;
    const int cend = (cbeg + 11 < NCHUNK) ? cbeg + 11 : NCHUNK;
    for (int c = cbeg; c < cend; ++c) {
      const unsigned dw = buf[c][lane];     // each slot read once, written once, same thread
      unsigned word = (unsigned)lane;
      if (c == NCHUNK - 1) {
        unsigned dws = dw << 24;
        wrec<8, 0>(word, dws, p.pdu, p.pdm, p.mrx);
      } else {
        unsigned dws = dw << 8;
        wrec<24, 0>(word, dws, p.pdu, p.pdm, p.mrx);
      }
      buf[c][lane] = word;
    }
  }
  __syncthreads();

  // ---- traceback: wave0, 86 chunk hops with prefetch ----
  if (wv == 0) {
    int lam = __builtin_amdgcn_readfirstlane(lam_sh);
    const size_t ob = (size_t)b * T_STEPS;
    unsigned row = buf[NCHUNK - 1][lane];
    for (int c = NCHUNK - 1; c >= 0; --c) {
      unsigned nrow = 0;
      if (c > 0) nrow = buf[c - 1][lane];          // prefetch (addr indep of lam)
      const unsigned w = (unsigned)__builtin_amdgcn_readlane((int)row, lam);
      const int nb = (c == NCHUNK - 1) ? 8 : 24;
      if (lane < nb) out[ob + c * 24 + lane] = (float)((w >> (6 + lane)) & 1u);
      lam = (int)(w & 63u);
      row = nrow;
    }
  }
}

extern "C" void kernel_launch(void* const* d_in, const int* in_sizes, int n_in,
                              void* d_out, int out_size, void* d_ws, size_t ws_size,
                              hipStream_t stream) {
  const float* in = (const float*)d_in[0];
  float* out = (float*)d_out;
  (void)in_sizes; (void)n_in; (void)out_size; (void)d_ws; (void)ws_size;
  vit_all<<<dim3(NB), dim3(512), 0, stream>>>(in, out);
}

// Round 18
// 65.850 us; speedup vs baseline: 1.0790x; 1.0400x over previous
//
#include <hip/hip_runtime.h>
#include <stdint.h>

#define T_STEPS 2048
#define NCHUNK  86            // 85 full 24-step chunks + one 8-step tail
#define LARGEF  1.0e9f
#define NB      512
typedef unsigned long long u64;
typedef unsigned uint2v __attribute__((ext_vector_type(2)));

__device__ __forceinline__ int par6(int x) { return __builtin_popcount((unsigned)x) & 1; }

// dual-basis functionals C; exchange masks m={1,2,7,15,16,32} (verified r2-r17)
constexpr int CARR[6] = {5, 6, 12, 8, 16, 32};

template<int CTRL>
__device__ __forceinline__ float xdpp(float x) {
  return __int_as_float(__builtin_amdgcn_update_dpp(0, __float_as_int(x), CTRL, 0xF, 0xF, true));
}
template<int CTRL>
__device__ __forceinline__ unsigned xdpp_u(unsigned x) {
  return (unsigned)__builtin_amdgcn_update_dpp(0, (int)x, CTRL, 0xF, 0xF, true);
}
__device__ __forceinline__ unsigned selmask_u(unsigned a_false, unsigned b_true, u64 m) {
  unsigned out;
  asm("v_cndmask_b32 %0, %1, %2, %3" : "=v"(out) : "v"(a_false), "v"(b_true), "s"(m));
  return out;
}
__device__ __forceinline__ unsigned exch16_u(unsigned x, u64 mrx) {
#if __has_builtin(__builtin_amdgcn_permlane16_swap)
  uint2v r = __builtin_amdgcn_permlane16_swap(x, x, false, false);
  return selmask_u(r.y, r.x, mrx);
#else
  (void)mrx;
  return (unsigned)__builtin_amdgcn_ds_swizzle((int)x, 0x401F);
#endif
}
__device__ __forceinline__ unsigned exch32_u(unsigned x, u64 mrx) {
#if __has_builtin(__builtin_amdgcn_permlane32_swap)
  uint2v r = __builtin_amdgcn_permlane32_swap(x, x, false, false);
  return selmask_u(r.y, r.x, mrx);
#else
  (void)mrx;
  return (unsigned)__shfl_xor((int)x, 32, 64);
#endif
}
template<int PH>
__device__ __forceinline__ float exchf(float x, const u64 (&mrx)[2]) {
  if constexpr (PH == 0) return xdpp<0xB1>(x);        // xor 1
  else if constexpr (PH == 1) return xdpp<0x4E>(x);   // xor 2
  else if constexpr (PH == 2) return xdpp<0x141>(x);  // xor 7
  else if constexpr (PH == 3) return xdpp<0x140>(x);  // xor 15
  else if constexpr (PH == 4) return __uint_as_float(exch16_u(__float_as_uint(x), mrx[0]));
  else return __uint_as_float(exch32_u(__float_as_uint(x), mrx[1]));
}
template<int PH>
__device__ __forceinline__ unsigned exchu(unsigned x, const u64 (&mrx)[2]) {
  if constexpr (PH == 0) return xdpp_u<0xB1>(x);
  else if constexpr (PH == 1) return xdpp_u<0x4E>(x);
  else if constexpr (PH == 2) return xdpp_u<0x141>(x);
  else if constexpr (PH == 3) return xdpp_u<0x140>(x);
  else if constexpr (PH == 4) return exch16_u(x, mrx[0]);
  else return exch32_u(x, mrx[1]);
}

struct Phc {
  float sae[6], sbe[6];
  unsigned clsm[6];  // v_cmp_class mask: pd ? (-inf|-norm|-den)=0x1C : (+den|+norm|+inf)=0x380
  unsigned pdu[6];   // decoded-bit constant per phase
  u64 pdm[6];        // uniform mask: lanes with odd own-pred parity
  u64 mrx[2];        // permlane swap r.x-select masks
};

__device__ __forceinline__ void mk_sasb(int lane, int ph, float& sae, float& sbe, int& pdv) {
  pdv = par6(lane & CARR[ph]);
  int t = 0;
#pragma unroll
  for (int j = 0; j < 5; ++j) t |= par6(lane & CARR[(ph + 1 + j) % 6]) << j;
  t |= pdv << 5;
  const float sa = 1.0f - 2.0f * (float)par6(t & 45);   // poly 1011011
  const float sb = 1.0f - 2.0f * (float)par6(t & 60);   // poly 1111001
  sae = pdv ? -sa : sa;
  sbe = pdv ? -sb : sb;
}

__device__ __forceinline__ void mk_mrx(int lane, u64 (&mrx)[2]) {
  const u64 ODD16 = 0xFFFF0000FFFF0000ull, HI32 = 0xFFFFFFFF00000000ull;
#if __has_builtin(__builtin_amdgcn_permlane16_swap)
  {
    uint2v r = __builtin_amdgcn_permlane16_swap((unsigned)lane, (unsigned)lane, false, false);
    mrx[0] = (((unsigned)__builtin_amdgcn_readlane((int)r.x, 0) == 16u)) ? ~ODD16 : ODD16;
  }
#else
  mrx[0] = 0;
#endif
#if __has_builtin(__builtin_amdgcn_permlane32_swap)
  {
    uint2v r = __builtin_amdgcn_permlane32_swap((unsigned)lane, (unsigned)lane, false, false);
    mrx[1] = (((unsigned)__builtin_amdgcn_readlane((int)r.x, 0) == 32u)) ? ~HI32 : HI32;
  }
#else
  mrx[1] = 0;
#endif
}

__device__ __forceinline__ void mkconsts(int lane, Phc& p) {
#pragma unroll
  for (int ph = 0; ph < 6; ++ph) {
    int pdv;
    mk_sasb(lane, ph, p.sae[ph], p.sbe[ph], pdv);
    p.clsm[ph] = pdv ? 0x01Cu : 0x380u;
    p.pdu[ph] = (unsigned)pdv;
    p.pdm[ph] = __ballot(pdv != 0);
  }
  mk_mrx(lane, p.mrx);
}

// ---- hoisted branch metrics for a chunk (independent ILP block) ----
template<int N>
__device__ __forceinline__ void bmcalc(const float4 (&fy)[12], float (&bm)[24],
                                       const float (&sae)[6], const float (&sbe)[6]) {
#pragma unroll
  for (int k = 0; k < N; ++k) {
    const int ph = k % 6;
    const float y0 = (k & 1) ? fy[k >> 1].z : fy[k >> 1].x;
    const float y1 = (k & 1) ? fy[k >> 1].w : fy[k >> 1].y;
    bm[k] = fmaf(sae[ph], y0, sbe[ph] * y1);   // bit-exact vs ref
  }
}

// ---- forward core: N ACS steps; dw = 2*dw + d (d_K lands at bit N-1-K) ----
// d via v_cmp_class(D, clsm): per-lane direction, tie(+-0) -> 0. == verified sign-xor rule.
template<int N, int K>
__device__ __forceinline__ void acs(float& cum, unsigned& dw, const float (&bm)[24],
                                    const unsigned (&clsm)[6], const u64 (&mrx)[2]) {
  if constexpr (K < N) {
    constexpr int ph = K % 6;
    const float ex = exchf<ph>(cum, mrx);
    const float cA = cum + bm[K];   // own-pred candidate
    const float cB = ex - bm[K];    // partner-pred candidate
    const float D = cA - cB;        // sign exact; zero iff true tie
    cum = fminf(cA, cB);
    asm("v_cmp_class_f32 vcc, %1, %2\n\t"
        "v_addc_co_u32 %0, vcc, %0, %0, vcc"
        : "+v"(dw) : "v"(D), "v"(clsm[ph]) : "vcc");
    acs<N, K + 1>(cum, dw, bm, clsm, mrx);
  }
}

// ---- chunk word reconstruction from d-bits (tp = d XOR pd; verified r10-r17) ----
template<int N, int K>
__device__ __forceinline__ void wrec(unsigned& word, unsigned& dws, const unsigned (&pdu)[6],
                                     const u64 (&pdm)[6], const u64 (&mrx)[2]) {
  if constexpr (K < N) {
    constexpr int ph = K % 6;
    const unsigned exw = exchu<ph>(word, mrx);
    asm("v_cmp_gt_i32 vcc, 0, %1\n\t"
        "v_add_u32 %1, %1, %1\n\t"
        "s_xor_b64 vcc, vcc, %3\n\t"
        "v_cndmask_b32 %0, %0, %2, vcc"
        : "+v"(word), "+v"(dws)
        : "v"(exw), "s"(pdm[ph]) : "vcc");
    word |= pdu[ph] << (6 + K);
    wrec<N, K + 1>(word, dws, pdu, pdm, mrx);
  }
}

// ---- terminal argmin over true states (tie -> smallest state) ----
__device__ __forceinline__ int term_argmin(float cum, int lane) {
  // final labeling = phase 2048%6 = 2: state bit j from C[(2+j)%6] = {12,8,16,32,5,6}
  const int stf = par6(lane & 12) | (par6(lane & 8) << 1) | (par6(lane & 16) << 2) |
                  (par6(lane & 32) << 3) | (par6(lane & 5) << 4) | (par6(lane & 6) << 5);
  float v = cum; int bs = stf; int bl = lane;
#pragma unroll
  for (int off = 32; off >= 1; off >>= 1) {
    const float ov = __shfl_xor(v, off, 64);
    const int os = __shfl_xor(bs, off, 64);
    const int ol = __shfl_xor(bl, off, 64);
    if (ov < v || (ov == v && os < bs)) { v = ov; bs = os; bl = ol; }
  }
  return bl;
}

// ========== fused kernel: wave FW forward -> 8-wave wrec (in-place) -> wave FW traceback ==========
// FW = hash(blockIdx) & 3: co-resident blocks on a CU get forward waves on DIFFERENT SIMDs
// (wave w -> SIMD w&3). r15's fixed wave0 piled both blocks' serial chains onto SIMD0,
// halving each chain's issue cadence. Hash distinct mod 4 for pair spacings {1,2,8,256}.
__global__ __launch_bounds__(512, 1) void vit_all(const float* __restrict__ in,
                                                  float* __restrict__ out) {
  __shared__ float y_lds[2 * T_STEPS];     // 16 KB staged input row
  __shared__ unsigned buf[NCHUNK][64];     // 21.5 KB: d-words, then path/anc words (in-place)
  __shared__ int lam_sh;

  const int tid = threadIdx.x;
  const int lane = tid & 63;
  const int wv = tid >> 6;
  const int b = blockIdx.x;
  const int FW = (b + (b >> 3) + (b >> 8)) & 3;

  // ---- stage y (8 waves, coalesced float4) ----
  {
    const float4* g = (const float4*)(in + (size_t)b * (2 * T_STEPS));
    float4* l = (float4*)y_lds;
    l[tid] = g[tid];
    l[tid + 512] = g[tid + 512];
  }
  Phc p;
  mkconsts(lane, p);
  __syncthreads();

  // ---- forward ACS (wave FW only; other waves wait at barrier, consuming no issue slots) ----
  if (wv == FW) {
    float cum = (lane == 0) ? 0.0f : LARGEF;
    float bm[24];
    float4 cur[12], nxt[12];
    const float4* y4 = (const float4*)y_lds;
    unsigned dw;
#pragma unroll
    for (int j = 0; j < 12; ++j) cur[j] = y4[j];               // chunk 0
    for (int cc = 0; cc < 42; ++cc) {
      const int c0 = 2 * cc;
      bmcalc<24>(cur, bm, p.sae, p.sbe);
#pragma unroll
      for (int j = 0; j < 12; ++j) nxt[j] = y4[12 * (c0 + 1) + j];   // prefetch c0+1
      dw = 0; acs<24, 0>(cum, dw, bm, p.clsm, p.mrx);
      buf[c0][lane] = dw;
      bmcalc<24>(nxt, bm, p.sae, p.sbe);
#pragma unroll
      for (int j = 0; j < 12; ++j) cur[j] = y4[12 * (c0 + 2) + j];   // prefetch c0+2
      dw = 0; acs<24, 0>(cum, dw, bm, p.clsm, p.mrx);
      buf[c0 + 1][lane] = dw;
    }
    // chunk 84 from cur; tail (steps 2040..2047) = float4 idx 1020..1023
    bmcalc<24>(cur, bm, p.sae, p.sbe);
#pragma unroll
    for (int j = 0; j < 4; ++j) nxt[j] = y4[1020 + j];
    dw = 0; acs<24, 0>(cum, dw, bm, p.clsm, p.mrx);
    buf[84][lane] = dw;
    bmcalc<8>(nxt, bm, p.sae, p.sbe);
    dw = 0; acs<8, 0>(cum, dw, bm, p.clsm, p.mrx);
    buf[85][lane] = dw;

    const int bl = term_argmin(cum, lane);
    if (lane == 0) lam_sh = bl;
  }
  __syncthreads();

  // ---- word reconstruction: 8 waves, ~11 chunks each, in-place on buf ----
  {
    const int cbeg = wv * 11;
    const int cend = (cbeg + 11 < NCHUNK) ? cbeg + 11 : NCHUNK;
    for (int c = cbeg; c < cend; ++c) {
      const unsigned dw = buf[c][lane];     // each slot read once, written once, same thread
      unsigned word = (unsigned)lane;
      if (c == NCHUNK - 1) {
        unsigned dws = dw << 24;
        wrec<8, 0>(word, dws, p.pdu, p.pdm, p.mrx);
      } else {
        unsigned dws = dw << 8;
        wrec<24, 0>(word, dws, p.pdu, p.pdm, p.mrx);
      }
      buf[c][lane] = word;
    }
  }
  __syncthreads();

  // ---- traceback: wave FW, 86 chunk hops with prefetch ----
  if (wv == FW) {
    int lam = __builtin_amdgcn_readfirstlane(lam_sh);
    const size_t ob = (size_t)b * T_STEPS;
    unsigned row = buf[NCHUNK - 1][lane];
    for (int c = NCHUNK - 1; c >= 0; --c) {
      unsigned nrow = 0;
      if (c > 0) nrow = buf[c - 1][lane];          // prefetch (addr indep of lam)
      const unsigned w = (unsigned)__builtin_amdgcn_readlane((int)row, lam);
      const int nb = (c == NCHUNK - 1) ? 8 : 24;
      if (lane < nb) out[ob + c * 24 + lane] = (float)((w >> (6 + lane)) & 1u);
      lam = (int)(w & 63u);
      row = nrow;
    }
  }
}

extern "C" void kernel_launch(void* const* d_in, const int* in_sizes, int n_in,
                              void* d_out, int out_size, void* d_ws, size_t ws_size,
                              hipStream_t stream) {
  const float* in = (const float*)d_in[0];
  float* out = (float*)d_out;
  (void)in_sizes; (void)n_in; (void)out_size; (void)d_ws; (void)ws_size;
  vit_all<<<dim3(NB), dim3(512), 0, stream>>>(in, out);
}